// Round 17
// baseline (80.309 us; speedup 1.0000x reference)
//
#include <hip/hip_runtime.h>
#include <hip/hip_bf16.h>

#define B_ROWS 8192
#define IN_DIM 1024
#define H_DIM  1024
#define WRANK  256
#define UR0    64
#define UR1    32
#define HGD    512

// stage-2 concat K = 256 + 64 + 32 = 352 -> 11 k-tiles of 32
#define NS2    11
// A2T: per 256-row panel, 14 physical k-tiles: 0..7 xw | 8,9 tU0 | 10 tUU1 | 11,12 tU1 | 13 tUU0
#define NTA    14
// tile image: [kc 0..3][rows][8 elems] ; 256-row tile = 8192 elems = 16KB

typedef __attribute__((ext_vector_type(8))) short bf16x8;
typedef __attribute__((ext_vector_type(4))) float f32x4;
typedef __attribute__((ext_vector_type(4))) float float4v;

__device__ __forceinline__ unsigned short f2bf(float f) {
    union { float f; unsigned u; } v; v.f = f;
    unsigned r = v.u + 0x7FFF + ((v.u >> 16) & 1);   // RNE
    return (unsigned short)(r >> 16);
}

// async 16B global->LDS copy (dest = wave-uniform base + lane*16)
__device__ __forceinline__ void gld16(void* lds, const void* g) {
    __builtin_amdgcn_global_load_lds(
        (const __attribute__((address_space(1))) unsigned int*)g,
        (__attribute__((address_space(3))) unsigned int*)lds, 16, 0, 0);
}

__device__ __forceinline__ float fsig(float x)  { return 1.f / (1.f + __expf(-x)); }
__device__ __forceinline__ float ftanh(float x) { return 1.f - 2.f / (__expf(2.f * x) + 1.f); }

// ---------------------------------------------------------------------------
// pack: s1's weight operands only (WbfT + HPbf).
// Formulas byte-identical to validated rounds 5-16.
// ---------------------------------------------------------------------------
__global__ __launch_bounds__(256)
void pack_weights(const float* __restrict__ W,
                  const float* __restrict__ U,  const float* __restrict__ UU,
                  unsigned short* __restrict__ WbfT,
                  unsigned short* __restrict__ HPbf)
{
    const long N_WT = 256L * 1024;
    const long N_HP = 256L * 512;
    const long total = N_WT + N_HP;
    for (long t = blockIdx.x * 256L + threadIdx.x; t < total; t += (long)gridDim.x * 256L) {
        if (t < N_WT) {
            int n = (int)(t >> 10), p = (int)(t & 1023);
            int span = p >> 6, slp = (p >> 3) & 7, e = p & 7;
            int k = span * 64 + ((slp ^ (n & 7)) << 3) + e;
            WbfT[t] = f2bf(W[(size_t)k * WRANK + n]);
        } else {
            long u = t - N_WT;
            int n = (int)(u >> 9), p = (int)(u & 511);
            int span = p >> 6, slp = (p >> 3) & 7, e = p & 7;
            int k = span * 64 + ((slp ^ (n & 7)) << 3) + e;
            float v;
            if (n < 64)       v = U [(size_t)k * UR0 + n];
            else if (n < 96)  v = UU[(size_t)(HGD + k) * UR1 + (n - 64)];
            else if (n < 128) v = 0.f;
            else if (n < 192) v = U [(size_t)(HGD + k) * UR0 + (n - 128)];
            else if (n < 224) v = UU[(size_t)k * UR1 + (n - 192)];
            else              v = 0.f;
            HPbf[u] = f2bf(v);
        }
    }
}

// ---------------------------------------------------------------------------
// stage 1: 1024 blocks, all co-resident (4/CU x 256 CU).
// x-path blocks (bx<4): 16 K-steps.  h-path blocks (bx>=4): 8 K-steps THEN
// a BT2-pack tail (pid=(bx-4)*128+by grid-stride over the validated BT2
// index space) — balances block runtimes and removes the extra 512 blocks.
// GEMM body byte-identical to validated rounds 5/8/10/12/15/16.
// ---------------------------------------------------------------------------
__global__ __launch_bounds__(256, 4)
void s1_kernel(const float* __restrict__ x, const float* __restrict__ h,
               const unsigned short* __restrict__ WbfT,
               const unsigned short* __restrict__ HPbf,
               unsigned short* __restrict__ A2T,
               unsigned short* __restrict__ BT2,
               const float* __restrict__ W1, const float* __restrict__ W2,
               const float* __restrict__ W3, const float* __restrict__ W4,
               const float* __restrict__ U1, const float* __restrict__ U2,
               const float* __restrict__ U3, const float* __restrict__ U4,
               const float* __restrict__ UU1, const float* __restrict__ UU2,
               const float* __restrict__ UU3, const float* __restrict__ UU4)
{
    __shared__ short As[64 * 64];        // 8 KB, single buffer
    __shared__ short Bs[2][64 * 64];     // 2 x 8 KB

    const int flat = blockIdx.x;                  // 1024 GEMM blocks
    const int id = (flat & 7) * 128 + (flat >> 3);
    const int bx = id & 7, by = id >> 3;
    const int m0 = by * 64;

    const bool pa = bx < 4;
    const int Kdim = pa ? IN_DIM : HGD;
    const float* Af = pa ? x : h;
    const int a_off = pa ? 0 : ((bx - 4) >> 1) * HGD;
    const unsigned short* Bw = pa ? (WbfT + (size_t)(bx * 64) * IN_DIM)
                                  : (HPbf + (size_t)((bx - 4) * 64) * HGD);
    const int ldbw = pa ? IN_DIM : HGD;
    const int ccol0 = pa ? bx * 64 : WRANK + (bx - 4) * 64;

    const int tid = threadIdx.x, lane = tid & 63, wid = tid >> 6;
    const int wr = wid >> 1, wc = wid & 1;
    const int lr = lane & 15, lh = lane >> 4;
    const int l8 = lane >> 3, l7 = lane & 7;

    f32x4 acc[2][2];
    #pragma unroll
    for (int i = 0; i < 2; ++i)
        #pragma unroll
        for (int j = 0; j < 2; ++j) acc[i][j] = (f32x4){0.f, 0.f, 0.f, 0.f};

    float4v areg[2][2][2];   // [set][chunk][half] -- static indices after unroll

#define S1_STAGEB(buf, kk) do {                                                   \
    _Pragma("unroll")                                                             \
    for (int t = 0; t < 2; ++t) {                                                 \
        int u = wid * 2 + t;                                                      \
        gld16((char*)&Bs[buf][0] + u * 1024,                                      \
              (const char*)Bw + ((size_t)(u * 8 + l8) * ldbw + (kk)) * 2 + l7 * 16); \
    } } while (0)

#define S1_LOADA(set, kk) do {                                                    \
    _Pragma("unroll")                                                             \
    for (int t = 0; t < 2; ++t) {                                                 \
        int cc = tid + t * 256;                                                   \
        int row = cc >> 3, slot = cc & 7;                                         \
        const float* p = Af + (size_t)(m0 + row) * 1024 + a_off + (kk) + slot * 8;\
        areg[set][t][0] = *(const float4v*)p;                                     \
        areg[set][t][1] = *(const float4v*)(p + 4);                               \
    } } while (0)

#define S1_WRITEA(set) do {                                                       \
    _Pragma("unroll")                                                             \
    for (int t = 0; t < 2; ++t) {                                                 \
        int cc = tid + t * 256;                                                   \
        int row = cc >> 3, slot = cc & 7;                                         \
        union { bf16x8 v; unsigned short s_[8]; } uv;                             \
        uv.s_[0] = f2bf(areg[set][t][0].x); uv.s_[1] = f2bf(areg[set][t][0].y);   \
        uv.s_[2] = f2bf(areg[set][t][0].z); uv.s_[3] = f2bf(areg[set][t][0].w);   \
        uv.s_[4] = f2bf(areg[set][t][1].x); uv.s_[5] = f2bf(areg[set][t][1].y);   \
        uv.s_[6] = f2bf(areg[set][t][1].z); uv.s_[7] = f2bf(areg[set][t][1].w);   \
        *(bf16x8*)((char*)As + row * 128 + ((slot ^ (row & 7)) << 4)) = uv.v;     \
    } } while (0)

    S1_STAGEB(0, 0);
    S1_LOADA(0, 0);

    #pragma unroll
    for (int ki = 0; ki < 16; ++ki) {
        if (ki * 64 >= Kdim) break;               // h-path: only 8 steps
        const int cur = ki & 1;
        const bool more = (ki + 1) * 64 < Kdim;
        if (more) S1_STAGEB(cur ^ 1, (ki + 1) * 64);
        if (more) { asm volatile("s_waitcnt vmcnt(2)" ::: "memory"); }
        else      { asm volatile("s_waitcnt vmcnt(0)" ::: "memory"); }
        S1_WRITEA(cur);
        if (more) S1_LOADA(cur ^ 1, (ki + 1) * 64);
        asm volatile("s_waitcnt lgkmcnt(0)" ::: "memory");
        __builtin_amdgcn_s_barrier();
        asm volatile("" ::: "memory");
        #pragma unroll
        for (int ks = 0; ks < 2; ++ks) {
            bf16x8 af[2];
            #pragma unroll
            for (int i = 0; i < 2; ++i) {
                int r = wr * 32 + i * 16 + lr;
                af[i] = *(const bf16x8*)((const char*)As + r * 128
                        + (((ks * 4 + lh) ^ (r & 7)) << 4));
            }
            #pragma unroll
            for (int j = 0; j < 2; ++j) {
                int r = wc * 32 + j * 16 + lr;
                bf16x8 rb = *(const bf16x8*)((const char*)&Bs[cur][0] + r * 128
                            + (((ks * 4 + lh) ^ (r & 7)) << 4));
                #pragma unroll
                for (int i = 0; i < 2; ++i)
                    acc[i][j] = __builtin_amdgcn_mfma_f32_16x16x32_bf16(
                        af[i], rb, acc[i][j], 0, 0, 0);
            }
        }
        asm volatile("" ::: "memory");
        __builtin_amdgcn_s_barrier();
        asm volatile("" ::: "memory");
    }
#undef S1_STAGEB
#undef S1_LOADA
#undef S1_WRITEA

    // epilogue: write A2T tile-image (skip zero-pad columns)
    #pragma unroll
    for (int i = 0; i < 2; ++i) {
        #pragma unroll
        for (int j = 0; j < 2; ++j) {
            int ncol = ccol0 + wc * 32 + j * 16 + lr;    // concat col 0..511
            int blk = ncol >> 5;
            if (blk == 11 || blk == 15) continue;        // pad columns
            int tt = (blk <= 10) ? blk : blk - 1;
            int kk = ncol & 31, kc = kk >> 3, e = kk & 7;
            #pragma unroll
            for (int rr = 0; rr < 4; ++rr) {
                int brow = m0 + wr * 32 + i * 16 + lh * 4 + rr;
                A2T[((size_t)(brow >> 8) * NTA + tt) * 8192 + kc * 2048
                    + (brow & 255) * 8 + e] = f2bf(acc[i][j][rr]);
            }
        }
    }

    // ---- BT2-pack tail on h-path blocks (balances 8-step vs 16-step) ----
    if (!pa) {
        const float* Wg[4]  = {W1, W2, W3, W4};
        const float* Ug[4]  = {U1, U2, U3, U4};
        const float* UUg[4] = {UU1, UU2, UU3, UU4};
        const int pid = (bx - 4) * 128 + by;             // 0..511
        const long N_BT = 16L * NS2 * 8192;
        for (long u = pid * 256L + threadIdx.x; u < N_BT; u += 512L * 256) {
            int img = (int)(u >> 13);            // nt*11 + s
            int nt = img / NS2, s = img % NS2;
            int r = (int)(u & 8191);
            int q = r >> 11, kc = (r >> 9) & 3, row = (r >> 3) & 63, e = r & 7;
            int n = nt * 64 + row, g = n >> 9, nn = n & 511;
            int kk = kc * 8 + e;
            float v;
            if (s < 8)       v = Wg[q][(size_t)(s * 32 + kk) * H_DIM + n];
            else if (s < 10) v = Ug[q][((size_t)g * UR0 + (s - 8) * 32 + kk) * HGD + nn];
            else             v = UUg[q][((size_t)g * UR1 + kk) * HGD + nn];
            BT2[u] = f2bf(v);
        }
    }
}

// ---------------------------------------------------------------------------
// stage 2: 4-gate MFMA GEMM (K=352, 11 k-tiles) + LSTM epilogue.
// VALIDATED round-15/16 version — byte-identical.
// ---------------------------------------------------------------------------
__global__ __launch_bounds__(512, 4)
void s2_kernel(const unsigned short* __restrict__ A2T,
               const unsigned short* __restrict__ BT2,
               const float* __restrict__ bias_f, const float* __restrict__ bias_i,
               const float* __restrict__ bias_c, const float* __restrict__ bias_o,
               const float* __restrict__ cin,
               float* __restrict__ cout, float* __restrict__ hout)
{
    __shared__ short As[3][4 * 128 * 8];     // 3 x 8 KB   [kc4][row128][8e]
    __shared__ short Bs[3][4 * 4 * 64 * 8];  // 3 x 16 KB  [q4][kc4][row64][8e]

    const int flat = blockIdx.x;                  // 1024 blocks, %8==0 -> bijective
    const int id = (flat & 7) * 128 + (flat >> 3);
    const int nt = id & 15, mt = id >> 4;         // mt-major within XCD
    const int m0 = mt * 128, n0 = nt * 64, g = nt >> 3;

    const int tid = threadIdx.x, lane = tid & 63, wid = tid >> 6;  // 8 waves
    const int wr = wid >> 2, wc = wid & 3;        // 2 (row) x 4 (col) wave grid
    const int lr = lane & 15, lh = lane >> 4;

    // A unit (per wave): kc = wid>>1, row-half = wid&1 within our 128 rows
    const char* Abase = (const char*)A2T + (size_t)(mt >> 1) * NTA * 16384
                        + (wid >> 1) * 4096 + (mt & 1) * 2048 + (wid & 1) * 1024
                        + lane * 16;
    const char* Bbase = (const char*)BT2 + (size_t)nt * NS2 * 16384 + lane * 16;

    f32x4 acc[4][4];   // [q][i]
    #pragma unroll
    for (int q = 0; q < 4; ++q)
        #pragma unroll
        for (int i = 0; i < 4; ++i) acc[q][i] = (f32x4){0.f, 0.f, 0.f, 0.f};

#define S2_TA(s) ((s) < 8 ? (s) : (g == 0 ? ((s) == 10 ? 13 : (s)) \
                                          : ((s) == 10 ? 10 : (s) + 3)))
    // one STAGE = exactly 3 gld16 per wave (1 A unit + 2 B units)
#define S2_STAGE(buf, s, tA) do {                                                 \
    gld16((char*)&As[buf][0] + wid * 1024, Abase + (size_t)(tA) * 16384);         \
    _Pragma("unroll")                                                             \
    for (int t = 0; t < 2; ++t) {                                                 \
        int v = wid * 2 + t;                                                      \
        gld16((char*)&Bs[buf][0] + v * 1024,                                      \
              Bbase + (size_t)(s) * 16384 + v * 1024);                            \
    } } while (0)

    S2_STAGE(0, 0, 0);
    S2_STAGE(1, 1, 1);

    #pragma unroll
    for (int s = 0; s < NS2; ++s) {
        const int cur = s % 3;
        if (s + 2 < NS2) {
            S2_STAGE((s + 2) % 3, s + 2, S2_TA(s + 2));
            asm volatile("s_waitcnt vmcnt(6)" ::: "memory");   // drain tile s only
        } else if (s + 1 < NS2) {
            asm volatile("s_waitcnt vmcnt(3)" ::: "memory");
        } else {
            asm volatile("s_waitcnt vmcnt(0)" ::: "memory");
        }
        __builtin_amdgcn_s_barrier();
        asm volatile("" ::: "memory");

        // ---- P0: af0,af1 + all rb; MFMA rows 0..31 of wave tile ----
        bf16x8 rb[4];
        #pragma unroll
        for (int q = 0; q < 4; ++q)
            rb[q] = *(const bf16x8*)((const char*)&Bs[cur][0]
                    + q * 4096 + lh * 1024 + (wc * 16 + lr) * 16);
        {
            bf16x8 af0 = *(const bf16x8*)((const char*)&As[cur][0]
                         + lh * 2048 + (wr * 64 + 0 * 16 + lr) * 16);
            bf16x8 af1 = *(const bf16x8*)((const char*)&As[cur][0]
                         + lh * 2048 + (wr * 64 + 1 * 16 + lr) * 16);
            __builtin_amdgcn_s_setprio(1);
            #pragma unroll
            for (int q = 0; q < 4; ++q) {
                acc[q][0] = __builtin_amdgcn_mfma_f32_16x16x32_bf16(af0, rb[q], acc[q][0], 0, 0, 0);
                acc[q][1] = __builtin_amdgcn_mfma_f32_16x16x32_bf16(af1, rb[q], acc[q][1], 0, 0, 0);
            }
            __builtin_amdgcn_s_setprio(0);
        }
        asm volatile("" ::: "memory");
        __builtin_amdgcn_s_barrier();     // mid-tile: anti-phase the waves
        asm volatile("" ::: "memory");

        // ---- P1: af2,af3; MFMA rows 32..63 ----
        {
            bf16x8 af2 = *(const bf16x8*)((const char*)&As[cur][0]
                         + lh * 2048 + (wr * 64 + 2 * 16 + lr) * 16);
            bf16x8 af3 = *(const bf16x8*)((const char*)&As[cur][0]
                         + lh * 2048 + (wr * 64 + 3 * 16 + lr) * 16);
            __builtin_amdgcn_s_setprio(1);
            #pragma unroll
            for (int q = 0; q < 4; ++q) {
                acc[q][2] = __builtin_amdgcn_mfma_f32_16x16x32_bf16(af2, rb[q], acc[q][2], 0, 0, 0);
                acc[q][3] = __builtin_amdgcn_mfma_f32_16x16x32_bf16(af3, rb[q], acc[q][3], 0, 0, 0);
            }
            __builtin_amdgcn_s_setprio(0);
        }
        asm volatile("" ::: "memory");
        __builtin_amdgcn_s_barrier();     // tile end: buf[cur] free for stage s+3
        asm volatile("" ::: "memory");
    }
#undef S2_STAGE
#undef S2_TA

    // epilogue: gates -> c_next, h_next (each thread owns one column)
    const int ncol = n0 + wc * 16 + lr;
    const float Bi = bias_i[ncol], Bf = bias_f[ncol];
    const float Bo = bias_o[ncol], Bc = bias_c[ncol];
    #pragma unroll
    for (int i = 0; i < 4; ++i) {
        #pragma unroll
        for (int rr = 0; rr < 4; ++rr) {
            int brow = m0 + wr * 64 + i * 16 + lh * 4 + rr;
            float mi = acc[0][i][rr] + Bi;
            float mf = acc[1][i][rr] + Bf;
            float mo = acc[2][i][rr] + Bo;
            float mc = acc[3][i][rr] + Bc;
            float iv = fsig(mi), fv = fsig(mf), ov = fsig(mo);
            float ct = ftanh(mc);
            float cv = cin[(size_t)brow * H_DIM + ncol];
            float cn = fv * cv + iv * ct;
            float hn = ov * ftanh(cn);
            cout[(size_t)brow * H_DIM + ncol] = cn;
            hout[(size_t)brow * H_DIM + ncol] = hn;
        }
    }
}

extern "C" void kernel_launch(void* const* d_in, const int* in_sizes, int n_in,
                              void* d_out, int out_size, void* d_ws, size_t ws_size,
                              hipStream_t stream)
{
    const float* x   = (const float*)d_in[0];
    const float* h   = (const float*)d_in[1];
    const float* c   = (const float*)d_in[2];
    const float* W   = (const float*)d_in[3];
    const float* W1  = (const float*)d_in[4];
    const float* W2  = (const float*)d_in[5];
    const float* W3  = (const float*)d_in[6];
    const float* W4  = (const float*)d_in[7];
    const float* U   = (const float*)d_in[8];
    const float* U1  = (const float*)d_in[9];
    const float* U2  = (const float*)d_in[10];
    const float* U3  = (const float*)d_in[11];
    const float* U4  = (const float*)d_in[12];
    const float* UU  = (const float*)d_in[13];
    const float* UU1 = (const float*)d_in[14];
    const float* UU2 = (const float*)d_in[15];
    const float* UU3 = (const float*)d_in[16];
    const float* UU4 = (const float*)d_in[17];
    const float* bias_f = (const float*)d_in[18];   // dict order: f, i, c, o
    const float* bias_i = (const float*)d_in[19];
    const float* bias_c = (const float*)d_in[20];
    const float* bias_o = (const float*)d_in[21];

    unsigned short* A2T  = (unsigned short*)d_ws;            // 32*14*8192 = 3,670,016
    unsigned short* WbfT = A2T  + 32L * NTA * 8192;          // 262,144
    unsigned short* HPbf = WbfT + 256L * 1024;               // 131,072
    unsigned short* BT2  = HPbf + 256L * 512;                // 16*11*8192 = 1,441,792

    float* c_out = (float*)d_out;
    float* h_out = c_out + (size_t)B_ROWS * H_DIM;

    pack_weights<<<dim3(512), dim3(256), 0, stream>>>(W, U, UU, WbfT, HPbf);

    s1_kernel<<<dim3(1024), dim3(256), 0, stream>>>(
        x, h, WbfT, HPbf, A2T, BT2,
        W1, W2, W3, W4, U1, U2, U3, U4, UU1, UU2, UU3, UU4);

    s2_kernel<<<dim3(1024), dim3(512), 0, stream>>>(
        A2T, BT2, bias_f, bias_i, bias_c, bias_o, c, c_out, h_out);
}

// Round 18
// 79.650 us; speedup vs baseline: 1.0083x; 1.0083x over previous
//
#include <hip/hip_runtime.h>
#include <hip/hip_bf16.h>

#define B_ROWS 8192
#define IN_DIM 1024
#define H_DIM  1024
#define WRANK  256
#define UR0    64
#define UR1    32
#define HGD    512

// stage-2 concat K = 256 + 64 + 32 = 352 -> 11 k-tiles of 32
#define NS2    11
// A2T: per 256-row panel, 14 physical k-tiles: 0..7 xw | 8,9 tU0 | 10 tUU1 | 11,12 tU1 | 13 tUU0
#define NTA    14
// tile image: [kc 0..3][rows][8 elems] ; 256-row tile = 8192 elems = 16KB

typedef __attribute__((ext_vector_type(8))) short bf16x8;
typedef __attribute__((ext_vector_type(4))) float f32x4;
typedef __attribute__((ext_vector_type(4))) float float4v;

__device__ __forceinline__ unsigned short f2bf(float f) {
    union { float f; unsigned u; } v; v.f = f;
    unsigned r = v.u + 0x7FFF + ((v.u >> 16) & 1);   // RNE
    return (unsigned short)(r >> 16);
}

// async 16B global->LDS copy (dest = wave-uniform base + lane*16)
__device__ __forceinline__ void gld16(void* lds, const void* g) {
    __builtin_amdgcn_global_load_lds(
        (const __attribute__((address_space(1))) unsigned int*)g,
        (__attribute__((address_space(3))) unsigned int*)lds, 16, 0, 0);
}

__device__ __forceinline__ float fsig(float x)  { return 1.f / (1.f + __expf(-x)); }
__device__ __forceinline__ float ftanh(float x) { return 1.f - 2.f / (__expf(2.f * x) + 1.f); }

// ---------------------------------------------------------------------------
// pack: s1's weight operands only (WbfT + HPbf); BT2 pack lives in s1 grid.
// Formulas byte-identical to validated rounds 5-16.
// ---------------------------------------------------------------------------
__global__ __launch_bounds__(256)
void pack_weights(const float* __restrict__ W,
                  const float* __restrict__ U,  const float* __restrict__ UU,
                  unsigned short* __restrict__ WbfT,
                  unsigned short* __restrict__ HPbf)
{
    const long N_WT = 256L * 1024;
    const long N_HP = 256L * 512;
    const long total = N_WT + N_HP;
    for (long t = blockIdx.x * 256L + threadIdx.x; t < total; t += (long)gridDim.x * 256L) {
        if (t < N_WT) {
            int n = (int)(t >> 10), p = (int)(t & 1023);
            int span = p >> 6, slp = (p >> 3) & 7, e = p & 7;
            int k = span * 64 + ((slp ^ (n & 7)) << 3) + e;
            WbfT[t] = f2bf(W[(size_t)k * WRANK + n]);
        } else {
            long u = t - N_WT;
            int n = (int)(u >> 9), p = (int)(u & 511);
            int span = p >> 6, slp = (p >> 3) & 7, e = p & 7;
            int k = span * 64 + ((slp ^ (n & 7)) << 3) + e;
            float v;
            if (n < 64)       v = U [(size_t)k * UR0 + n];
            else if (n < 96)  v = UU[(size_t)(HGD + k) * UR1 + (n - 64)];
            else if (n < 128) v = 0.f;
            else if (n < 192) v = U [(size_t)(HGD + k) * UR0 + (n - 128)];
            else if (n < 224) v = UU[(size_t)k * UR1 + (n - 192)];
            else              v = 0.f;
            HPbf[u] = f2bf(v);
        }
    }
}

// ---------------------------------------------------------------------------
// stage 1: blocks 0..1023 = VALIDATED r5/8/10/12/15 GEMM (byte-identical);
// blocks 1024..1535 pack BT2 (write-only, no LDS/sync; consumed only by s2;
// formula byte-identical to the validated pack_weights BT2 branch).
// ---------------------------------------------------------------------------
__global__ __launch_bounds__(256, 4)
void s1_kernel(const float* __restrict__ x, const float* __restrict__ h,
               const unsigned short* __restrict__ WbfT,
               const unsigned short* __restrict__ HPbf,
               unsigned short* __restrict__ A2T,
               unsigned short* __restrict__ BT2,
               const float* __restrict__ W1, const float* __restrict__ W2,
               const float* __restrict__ W3, const float* __restrict__ W4,
               const float* __restrict__ U1, const float* __restrict__ U2,
               const float* __restrict__ U3, const float* __restrict__ U4,
               const float* __restrict__ UU1, const float* __restrict__ UU2,
               const float* __restrict__ UU3, const float* __restrict__ UU4)
{
    __shared__ short As[64 * 64];        // 8 KB, single buffer
    __shared__ short Bs[2][64 * 64];     // 2 x 8 KB

    if (blockIdx.x >= 1024) {            // ---- BT2 pack blocks ----
        const float* Wg[4]  = {W1, W2, W3, W4};
        const float* Ug[4]  = {U1, U2, U3, U4};
        const float* UUg[4] = {UU1, UU2, UU3, UU4};
        const long N_BT = 16L * NS2 * 8192;
        for (long u = (blockIdx.x - 1024) * 256L + threadIdx.x; u < N_BT;
             u += 512L * 256) {
            int img = (int)(u >> 13);            // nt*11 + s
            int nt = img / NS2, s = img % NS2;
            int r = (int)(u & 8191);
            int q = r >> 11, kc = (r >> 9) & 3, row = (r >> 3) & 63, e = r & 7;
            int n = nt * 64 + row, g = n >> 9, nn = n & 511;
            int kk = kc * 8 + e;
            float v;
            if (s < 8)       v = Wg[q][(size_t)(s * 32 + kk) * H_DIM + n];
            else if (s < 10) v = Ug[q][((size_t)g * UR0 + (s - 8) * 32 + kk) * HGD + nn];
            else             v = UUg[q][((size_t)g * UR1 + kk) * HGD + nn];
            BT2[u] = f2bf(v);
        }
        return;
    }

    const int flat = blockIdx.x;                  // 1024 GEMM blocks
    const int id = (flat & 7) * 128 + (flat >> 3);
    const int bx = id & 7, by = id >> 3;
    const int m0 = by * 64;

    const bool pa = bx < 4;
    const int Kdim = pa ? IN_DIM : HGD;
    const float* Af = pa ? x : h;
    const int a_off = pa ? 0 : ((bx - 4) >> 1) * HGD;
    const unsigned short* Bw = pa ? (WbfT + (size_t)(bx * 64) * IN_DIM)
                                  : (HPbf + (size_t)((bx - 4) * 64) * HGD);
    const int ldbw = pa ? IN_DIM : HGD;
    const int ccol0 = pa ? bx * 64 : WRANK + (bx - 4) * 64;

    const int tid = threadIdx.x, lane = tid & 63, wid = tid >> 6;
    const int wr = wid >> 1, wc = wid & 1;
    const int lr = lane & 15, lh = lane >> 4;
    const int l8 = lane >> 3, l7 = lane & 7;

    f32x4 acc[2][2];
    #pragma unroll
    for (int i = 0; i < 2; ++i)
        #pragma unroll
        for (int j = 0; j < 2; ++j) acc[i][j] = (f32x4){0.f, 0.f, 0.f, 0.f};

    float4v areg[2][2][2];   // [set][chunk][half] -- static indices after unroll

#define S1_STAGEB(buf, kk) do {                                                   \
    _Pragma("unroll")                                                             \
    for (int t = 0; t < 2; ++t) {                                                 \
        int u = wid * 2 + t;                                                      \
        gld16((char*)&Bs[buf][0] + u * 1024,                                      \
              (const char*)Bw + ((size_t)(u * 8 + l8) * ldbw + (kk)) * 2 + l7 * 16); \
    } } while (0)

#define S1_LOADA(set, kk) do {                                                    \
    _Pragma("unroll")                                                             \
    for (int t = 0; t < 2; ++t) {                                                 \
        int cc = tid + t * 256;                                                   \
        int row = cc >> 3, slot = cc & 7;                                         \
        const float* p = Af + (size_t)(m0 + row) * 1024 + a_off + (kk) + slot * 8;\
        areg[set][t][0] = *(const float4v*)p;                                     \
        areg[set][t][1] = *(const float4v*)(p + 4);                               \
    } } while (0)

#define S1_WRITEA(set) do {                                                       \
    _Pragma("unroll")                                                             \
    for (int t = 0; t < 2; ++t) {                                                 \
        int cc = tid + t * 256;                                                   \
        int row = cc >> 3, slot = cc & 7;                                         \
        union { bf16x8 v; unsigned short s_[8]; } uv;                             \
        uv.s_[0] = f2bf(areg[set][t][0].x); uv.s_[1] = f2bf(areg[set][t][0].y);   \
        uv.s_[2] = f2bf(areg[set][t][0].z); uv.s_[3] = f2bf(areg[set][t][0].w);   \
        uv.s_[4] = f2bf(areg[set][t][1].x); uv.s_[5] = f2bf(areg[set][t][1].y);   \
        uv.s_[6] = f2bf(areg[set][t][1].z); uv.s_[7] = f2bf(areg[set][t][1].w);   \
        *(bf16x8*)((char*)As + row * 128 + ((slot ^ (row & 7)) << 4)) = uv.v;     \
    } } while (0)

    S1_STAGEB(0, 0);
    S1_LOADA(0, 0);

    #pragma unroll
    for (int ki = 0; ki < 16; ++ki) {
        if (ki * 64 >= Kdim) break;               // h-path: only 8 steps
        const int cur = ki & 1;
        const bool more = (ki + 1) * 64 < Kdim;
        if (more) S1_STAGEB(cur ^ 1, (ki + 1) * 64);
        if (more) { asm volatile("s_waitcnt vmcnt(2)" ::: "memory"); }
        else      { asm volatile("s_waitcnt vmcnt(0)" ::: "memory"); }
        S1_WRITEA(cur);
        if (more) S1_LOADA(cur ^ 1, (ki + 1) * 64);
        asm volatile("s_waitcnt lgkmcnt(0)" ::: "memory");
        __builtin_amdgcn_s_barrier();
        asm volatile("" ::: "memory");
        #pragma unroll
        for (int ks = 0; ks < 2; ++ks) {
            bf16x8 af[2];
            #pragma unroll
            for (int i = 0; i < 2; ++i) {
                int r = wr * 32 + i * 16 + lr;
                af[i] = *(const bf16x8*)((const char*)As + r * 128
                        + (((ks * 4 + lh) ^ (r & 7)) << 4));
            }
            #pragma unroll
            for (int j = 0; j < 2; ++j) {
                int r = wc * 32 + j * 16 + lr;
                bf16x8 rb = *(const bf16x8*)((const char*)&Bs[cur][0] + r * 128
                            + (((ks * 4 + lh) ^ (r & 7)) << 4));
                #pragma unroll
                for (int i = 0; i < 2; ++i)
                    acc[i][j] = __builtin_amdgcn_mfma_f32_16x16x32_bf16(
                        af[i], rb, acc[i][j], 0, 0, 0);
            }
        }
        asm volatile("" ::: "memory");
        __builtin_amdgcn_s_barrier();
        asm volatile("" ::: "memory");
    }
#undef S1_STAGEB
#undef S1_LOADA
#undef S1_WRITEA

    // epilogue: write A2T tile-image (skip zero-pad columns)
    #pragma unroll
    for (int i = 0; i < 2; ++i) {
        #pragma unroll
        for (int j = 0; j < 2; ++j) {
            int ncol = ccol0 + wc * 32 + j * 16 + lr;    // concat col 0..511
            int blk = ncol >> 5;
            if (blk == 11 || blk == 15) continue;        // pad columns
            int tt = (blk <= 10) ? blk : blk - 1;
            int kk = ncol & 31, kc = kk >> 3, e = kk & 7;
            #pragma unroll
            for (int rr = 0; rr < 4; ++rr) {
                int brow = m0 + wr * 32 + i * 16 + lh * 4 + rr;
                A2T[((size_t)(brow >> 8) * NTA + tt) * 8192 + kc * 2048
                    + (brow & 255) * 8 + e] = f2bf(acc[i][j][rr]);
            }
        }
    }
}

// ---------------------------------------------------------------------------
// stage 2: 4-gate MFMA GEMM (K=352, 11 k-tiles) + LSTM epilogue.
// VALIDATED round-15/16 version — byte-identical.
// ---------------------------------------------------------------------------
__global__ __launch_bounds__(512, 4)
void s2_kernel(const unsigned short* __restrict__ A2T,
               const unsigned short* __restrict__ BT2,
               const float* __restrict__ bias_f, const float* __restrict__ bias_i,
               const float* __restrict__ bias_c, const float* __restrict__ bias_o,
               const float* __restrict__ cin,
               float* __restrict__ cout, float* __restrict__ hout)
{
    __shared__ short As[3][4 * 128 * 8];     // 3 x 8 KB   [kc4][row128][8e]
    __shared__ short Bs[3][4 * 4 * 64 * 8];  // 3 x 16 KB  [q4][kc4][row64][8e]

    const int flat = blockIdx.x;                  // 1024 blocks, %8==0 -> bijective
    const int id = (flat & 7) * 128 + (flat >> 3);
    const int nt = id & 15, mt = id >> 4;         // mt-major within XCD
    const int m0 = mt * 128, n0 = nt * 64, g = nt >> 3;

    const int tid = threadIdx.x, lane = tid & 63, wid = tid >> 6;  // 8 waves
    const int wr = wid >> 2, wc = wid & 3;        // 2 (row) x 4 (col) wave grid
    const int lr = lane & 15, lh = lane >> 4;

    // A unit (per wave): kc = wid>>1, row-half = wid&1 within our 128 rows
    const char* Abase = (const char*)A2T + (size_t)(mt >> 1) * NTA * 16384
                        + (wid >> 1) * 4096 + (mt & 1) * 2048 + (wid & 1) * 1024
                        + lane * 16;
    const char* Bbase = (const char*)BT2 + (size_t)nt * NS2 * 16384 + lane * 16;

    f32x4 acc[4][4];   // [q][i]
    #pragma unroll
    for (int q = 0; q < 4; ++q)
        #pragma unroll
        for (int i = 0; i < 4; ++i) acc[q][i] = (f32x4){0.f, 0.f, 0.f, 0.f};

#define S2_TA(s) ((s) < 8 ? (s) : (g == 0 ? ((s) == 10 ? 13 : (s)) \
                                          : ((s) == 10 ? 10 : (s) + 3)))
    // one STAGE = exactly 3 gld16 per wave (1 A unit + 2 B units)
#define S2_STAGE(buf, s, tA) do {                                                 \
    gld16((char*)&As[buf][0] + wid * 1024, Abase + (size_t)(tA) * 16384);         \
    _Pragma("unroll")                                                             \
    for (int t = 0; t < 2; ++t) {                                                 \
        int v = wid * 2 + t;                                                      \
        gld16((char*)&Bs[buf][0] + v * 1024,                                      \
              Bbase + (size_t)(s) * 16384 + v * 1024);                            \
    } } while (0)

    S2_STAGE(0, 0, 0);
    S2_STAGE(1, 1, 1);

    #pragma unroll
    for (int s = 0; s < NS2; ++s) {
        const int cur = s % 3;
        if (s + 2 < NS2) {
            S2_STAGE((s + 2) % 3, s + 2, S2_TA(s + 2));
            asm volatile("s_waitcnt vmcnt(6)" ::: "memory");   // drain tile s only
        } else if (s + 1 < NS2) {
            asm volatile("s_waitcnt vmcnt(3)" ::: "memory");
        } else {
            asm volatile("s_waitcnt vmcnt(0)" ::: "memory");
        }
        __builtin_amdgcn_s_barrier();
        asm volatile("" ::: "memory");

        // ---- P0: af0,af1 + all rb; MFMA rows 0..31 of wave tile ----
        bf16x8 rb[4];
        #pragma unroll
        for (int q = 0; q < 4; ++q)
            rb[q] = *(const bf16x8*)((const char*)&Bs[cur][0]
                    + q * 4096 + lh * 1024 + (wc * 16 + lr) * 16);
        {
            bf16x8 af0 = *(const bf16x8*)((const char*)&As[cur][0]
                         + lh * 2048 + (wr * 64 + 0 * 16 + lr) * 16);
            bf16x8 af1 = *(const bf16x8*)((const char*)&As[cur][0]
                         + lh * 2048 + (wr * 64 + 1 * 16 + lr) * 16);
            __builtin_amdgcn_s_setprio(1);
            #pragma unroll
            for (int q = 0; q < 4; ++q) {
                acc[q][0] = __builtin_amdgcn_mfma_f32_16x16x32_bf16(af0, rb[q], acc[q][0], 0, 0, 0);
                acc[q][1] = __builtin_amdgcn_mfma_f32_16x16x32_bf16(af1, rb[q], acc[q][1], 0, 0, 0);
            }
            __builtin_amdgcn_s_setprio(0);
        }
        asm volatile("" ::: "memory");
        __builtin_amdgcn_s_barrier();     // mid-tile: anti-phase the waves
        asm volatile("" ::: "memory");

        // ---- P1: af2,af3; MFMA rows 32..63 ----
        {
            bf16x8 af2 = *(const bf16x8*)((const char*)&As[cur][0]
                         + lh * 2048 + (wr * 64 + 2 * 16 + lr) * 16);
            bf16x8 af3 = *(const bf16x8*)((const char*)&As[cur][0]
                         + lh * 2048 + (wr * 64 + 3 * 16 + lr) * 16);
            __builtin_amdgcn_s_setprio(1);
            #pragma unroll
            for (int q = 0; q < 4; ++q) {
                acc[q][2] = __builtin_amdgcn_mfma_f32_16x16x32_bf16(af2, rb[q], acc[q][2], 0, 0, 0);
                acc[q][3] = __builtin_amdgcn_mfma_f32_16x16x32_bf16(af3, rb[q], acc[q][3], 0, 0, 0);
            }
            __builtin_amdgcn_s_setprio(0);
        }
        asm volatile("" ::: "memory");
        __builtin_amdgcn_s_barrier();     // tile end: buf[cur] free for stage s+3
        asm volatile("" ::: "memory");
    }
#undef S2_STAGE
#undef S2_TA

    // epilogue: gates -> c_next, h_next (each thread owns one column)
    const int ncol = n0 + wc * 16 + lr;
    const float Bi = bias_i[ncol], Bf = bias_f[ncol];
    const float Bo = bias_o[ncol], Bc = bias_c[ncol];
    #pragma unroll
    for (int i = 0; i < 4; ++i) {
        #pragma unroll
        for (int rr = 0; rr < 4; ++rr) {
            int brow = m0 + wr * 64 + i * 16 + lh * 4 + rr;
            float mi = acc[0][i][rr] + Bi;
            float mf = acc[1][i][rr] + Bf;
            float mo = acc[2][i][rr] + Bo;
            float mc = acc[3][i][rr] + Bc;
            float iv = fsig(mi), fv = fsig(mf), ov = fsig(mo);
            float ct = ftanh(mc);
            float cv = cin[(size_t)brow * H_DIM + ncol];
            float cn = fv * cv + iv * ct;
            float hn = ov * ftanh(cn);
            cout[(size_t)brow * H_DIM + ncol] = cn;
            hout[(size_t)brow * H_DIM + ncol] = hn;
        }
    }
}

extern "C" void kernel_launch(void* const* d_in, const int* in_sizes, int n_in,
                              void* d_out, int out_size, void* d_ws, size_t ws_size,
                              hipStream_t stream)
{
    const float* x   = (const float*)d_in[0];
    const float* h   = (const float*)d_in[1];
    const float* c   = (const float*)d_in[2];
    const float* W   = (const float*)d_in[3];
    const float* W1  = (const float*)d_in[4];
    const float* W2  = (const float*)d_in[5];
    const float* W3  = (const float*)d_in[6];
    const float* W4  = (const float*)d_in[7];
    const float* U   = (const float*)d_in[8];
    const float* U1  = (const float*)d_in[9];
    const float* U2  = (const float*)d_in[10];
    const float* U3  = (const float*)d_in[11];
    const float* U4  = (const float*)d_in[12];
    const float* UU  = (const float*)d_in[13];
    const float* UU1 = (const float*)d_in[14];
    const float* UU2 = (const float*)d_in[15];
    const float* UU3 = (const float*)d_in[16];
    const float* UU4 = (const float*)d_in[17];
    const float* bias_f = (const float*)d_in[18];   // dict order: f, i, c, o
    const float* bias_i = (const float*)d_in[19];
    const float* bias_c = (const float*)d_in[20];
    const float* bias_o = (const float*)d_in[21];

    unsigned short* A2T  = (unsigned short*)d_ws;            // 32*14*8192 = 3,670,016
    unsigned short* WbfT = A2T  + 32L * NTA * 8192;          // 262,144
    unsigned short* HPbf = WbfT + 256L * 1024;               // 131,072
    unsigned short* BT2  = HPbf + 256L * 512;                // 16*11*8192 = 1,441,792

    float* c_out = (float*)d_out;
    float* h_out = c_out + (size_t)B_ROWS * H_DIM;

    pack_weights<<<dim3(512), dim3(256), 0, stream>>>(W, U, UU, WbfT, HPbf);

    s1_kernel<<<dim3(1536), dim3(256), 0, stream>>>(
        x, h, WbfT, HPbf, A2T, BT2,
        W1, W2, W3, W4, U1, U2, U3, U4, UU1, UU2, UU3, UU4);

    s2_kernel<<<dim3(1024), dim3(512), 0, stream>>>(
        A2T, BT2, bias_f, bias_i, bias_c, bias_o, c, c_out, h_out);
}